// Round 5
// baseline (64.517 us; speedup 1.0000x reference)
//
#include <hip/hip_runtime.h>
#include <math.h>

constexpr int NB = 8, NC = 64, NO = 64, NH = 64, NW = 64, NA = 4, NKK = 9;

using f32x4 = __attribute__((ext_vector_type(4))) float;
using s16x8 = __attribute__((ext_vector_type(8))) short;

__device__ __forceinline__ unsigned short f2bf(float f) {
    unsigned u = __builtin_bit_cast(unsigned, f);
    return (unsigned short)((u + 0x7fffu + ((u >> 16) & 1u)) >> 16);
}

__device__ __forceinline__ void gload16(const void* gsrc, void* ldst) {
    __builtin_amdgcn_global_load_lds(
        (const __attribute__((address_space(1))) unsigned int*)gsrc,
        (__attribute__((address_space(3))) unsigned int*)ldst,
        16, 0, 0);
}

// ---------- pre-kernel: bf16 swizzled W image + transposed bias into d_ws ----------
// W image: per (osub,k): 16 KB block at (osub*9+k)*16384; within block:
//   byte = a*4096 + o_l*128 + ((cseg*16) ^ ((o_l&7)<<4)); 16B = 8 bf16 of channels cseg*8..+8
//   source row f = ((osub*32+o_l)*4 + a)*9 + k  of w_gen[2304][64]
// Bias image at 294912: f32 [osub][k][a][o_l]
__global__ void acda_prep(const float* __restrict__ w_gen,
                          const float* __restrict__ b_gen,
                          unsigned char* __restrict__ ws) {
    const int g = blockIdx.x * 512 + threadIdx.x;    // 0..18431
    {
        const int cseg = g & 7;
        const int o_l  = (g >> 3) & 31;
        const int a    = (g >> 8) & 3;
        const int kt   = g >> 10;                    // 0..17
        const int osub = kt / 9, k = kt - 9 * osub;
        const int f = ((osub * 32 + o_l) * 4 + a) * 9 + k;
        const float* src = w_gen + (size_t)f * NC + cseg * 8;
        s16x8 pk;
#pragma unroll
        for (int j = 0; j < 8; ++j) pk[j] = (short)f2bf(src[j]);
        const int byte = kt * 16384 + a * 4096 + o_l * 128 + ((cseg * 16) ^ ((o_l & 7) << 4));
        *reinterpret_cast<s16x8*>(ws + byte) = pk;
    }
    if (g < 2304) {
        const int osub = g / 1152, r = g % 1152;
        const int k = r >> 7, a = (r >> 5) & 3, o_l = r & 31;
        reinterpret_cast<float*>(ws + 294912)[g] =
            b_gen[((osub * 32 + o_l) * 4 + a) * 9 + k];
    }
}

// ---------- main kernel ----------
// Grid 256 = b(8) x hgrp(16) x osub(2). Block 512 = 8 waves.
// Block tile: 4 h-rows x 64 w (256 locs) x 32 o. Wave: ofrag = wv&1 (16 o), lt = wv>>1 (h-row),
// 4 n-tiles of 16 w. MFMA A = W (rows=o), B = x (cols=w).
// D: row(o) = q*4+reg, col(w) = c0 -> coalesced stores.
template <bool USE_WS>
__global__ __launch_bounds__(512, 2)
void acda_main(const float* __restrict__ x, const float* __restrict__ w_gen,
               const float* __restrict__ b_gen, const float* __restrict__ pos_enc,
               const unsigned char* __restrict__ ws, float* __restrict__ out)
{
    __shared__ __align__(16) unsigned char arena[57024];  // Xs (32KB) then Patch f32 (57KB)
    __shared__ __align__(16) unsigned short Wb[2][4][32 * 64];  // 32 KB dbuf x 4 atoms
    __shared__ float BiasL[1152];                               // [k][a][o_l]

    unsigned short* Xs = reinterpret_cast<unsigned short*>(arena);  // [loc 256][c 64] swz
    float* Patch = reinterpret_cast<float*>(arena);                 // [hhi 6][wwi 66][36]

    const int tid = threadIdx.x, lane = tid & 63, wv = tid >> 6;
    const int c0 = lane & 15, q = lane >> 4;
    const int ofrag = wv & 1, lt = wv >> 1;
    const int bx = blockIdx.x;
    const int osub = bx & 1;
    const int hg   = (bx >> 1) & 15;
    const int b    = bx >> 5;
    const int hbase = hg * 4, obase = osub * 32;
    const size_t xB = (size_t)b * NC * NH * NW;

    // ---- stage Xs: x[b,c,hbase+hs,w] -> Xs[loc=hs*64+w][c] bf16 swizzled ----
    {
        const int w = lane, oct = wv;
#pragma unroll
        for (int hs = 0; hs < 4; ++hs) {
            s16x8 pk;
#pragma unroll
            for (int j = 0; j < 8; ++j)
                pk[j] = (short)f2bf(x[xB + (size_t)(oct * 8 + j) * (NH * NW) + (hbase + hs) * NW + w]);
            const int loc = hs * 64 + w;
            const int byte = loc * 128 + ((oct * 16) ^ ((loc & 7) << 4));
            *reinterpret_cast<s16x8*>(arena + byte) = pk;
        }
    }
    __syncthreads();
    // ---- x fragments ----
    s16x8 xf[4][2];
#pragma unroll
    for (int nt = 0; nt < 4; ++nt) {
        const int loc = lt * 64 + nt * 16 + c0;
#pragma unroll
        for (int kh2 = 0; kh2 < 2; ++kh2) {
            const int byte = loc * 128 + ((kh2 * 64 + q * 16) ^ ((loc & 7) << 4));
            xf[nt][kh2] = *reinterpret_cast<s16x8*>(arena + byte);
        }
    }
    __syncthreads();   // all Xs reads done; arena becomes Patch

    // ---- W stage (k -> Wb[nbuf]) ----
    auto stageW = [&](int k, int nbuf) {
        if constexpr (USE_WS) {
            const unsigned char* src = ws + (size_t)(osub * 9 + k) * 16384;
            unsigned char* dst = reinterpret_cast<unsigned char*>(&Wb[nbuf][0][0]);
#pragma unroll
            for (int half = 0; half < 2; ++half) {
                const int off = half * 8192 + wv * 1024;
                gload16(src + off + lane * 16, dst + off);
            }
        } else {
            const int a = tid >> 7, o_l = (tid >> 2) & 31, cs = (tid & 3) * 16;
            const int f = ((obase + o_l) * 4 + a) * 9 + k;
            const float* src = w_gen + (size_t)f * NC + cs;
#pragma unroll
            for (int j = 0; j < 2; ++j) {
                s16x8 pk;
#pragma unroll
                for (int t = 0; t < 8; ++t) pk[t] = (short)f2bf(src[j * 8 + t]);
                const int cseg = (cs >> 3) + j;
                const int byte = a * 4096 + o_l * 128 + ((cseg * 16) ^ ((o_l & 7) << 4));
                *reinterpret_cast<s16x8*>(
                    reinterpret_cast<unsigned char*>(&Wb[nbuf][0][0]) + byte) = pk;
            }
        }
    };
    stageW(0, 0);

    // ---- stage Patch f32: x[b,obase+o_l,hbase-1+hhi,ww] -> Patch[hhi][ww+1][o_l] ----
    {
        const int o_l = tid >> 4, i4 = (tid & 15) * 4;
        const float* xo = x + xB + (size_t)(obase + o_l) * (NH * NW);
#pragma unroll
        for (int hhi = 0; hhi < 6; ++hhi) {
            const int hh = hbase - 1 + hhi;
            float4 v = {0.f, 0.f, 0.f, 0.f};
            if (hh >= 0 && hh < NH) v = *reinterpret_cast<const float4*>(xo + hh * NW + i4);
            float* p = Patch + (hhi * 66 + i4 + 1) * 36 + o_l;
            p[0] = v.x; p[36] = v.y; p[72] = v.z; p[108] = v.w;
        }
        if (tid < 384) {   // halo columns wwi = 0, 65
            const int hhi = tid >> 6, side = (tid >> 5) & 1, ol2 = tid & 31;
            Patch[(hhi * 66 + (side ? 65 : 0)) * 36 + ol2] = 0.f;
        }
    }
    // ---- bias ----
    if constexpr (USE_WS) {
        const float* bs = reinterpret_cast<const float*>(ws + 294912) + osub * 1152;
        for (int i = tid; i < 1152; i += 512) BiasL[i] = bs[i];
    } else {
        for (int i = tid; i < 1152; i += 512) {
            const int k = i >> 7, a = (i >> 5) & 3, o_l = i & 31;
            BiasL[i] = b_gen[((obase + o_l) * 4 + a) * 9 + k];
        }
    }

    // ---- attention weights attv[a][nt] (per-lane scalars) ----
    float pe[8];
#pragma unroll
    for (int i = 0; i < 8; ++i) pe[i] = pos_enc[i];
    const float gy = -1.0f + (2.0f / 63.0f) * (float)(hbase + lt);
    float attv[4][4];
#pragma unroll
    for (int a = 0; a < 4; ++a)
#pragma unroll
        for (int nt = 0; nt < 4; ++nt) {
            const float gx = -1.0f + (2.0f / 63.0f) * (float)(nt * 16 + c0);
            const float dx = gx - pe[2 * a], dy = gy - pe[2 * a + 1];
            attv[a][nt] = __expf(-(dx * dx + dy * dy));
        }

    __syncthreads();   // Wb[0], Patch, BiasL ready

    const int o4 = ofrag * 16 + q * 4;
    const int wrow = ofrag * 16 + c0;
    const int swz = (wrow & 7) << 4;
    const float* pb0 = Patch + (lt * 66 + c0) * 36 + o4;   // + (kh*66 + nt*16 + kw)*36

    float outacc[4][4] = {};

#pragma unroll
    for (int k = 0; k < 9; ++k) {
        const int buf = k & 1;
        if (k < 8) stageW(k + 1, buf ^ 1);
        float tsum[4][4] = {};
#pragma unroll
        for (int a = 0; a < 4; ++a) {
            const unsigned char* Wt = reinterpret_cast<const unsigned char*>(&Wb[buf][a][0]);
            const s16x8 wf0 = *reinterpret_cast<const s16x8*>(Wt + wrow * 128 + ((q * 16) ^ swz));
            const s16x8 wf1 = *reinterpret_cast<const s16x8*>(Wt + wrow * 128 + ((64 + q * 16) ^ swz));
            const f32x4 bb = *reinterpret_cast<const f32x4*>(BiasL + (k * 4 + a) * 32 + o4);
#pragma unroll
            for (int nt = 0; nt < 4; ++nt) {
                f32x4 acc = bb;
                acc = __builtin_amdgcn_mfma_f32_16x16x32_bf16(wf0, xf[nt][0], acc, 0, 0, 0);
                acc = __builtin_amdgcn_mfma_f32_16x16x32_bf16(wf1, xf[nt][1], acc, 0, 0, 0);
                const float at = attv[a][nt];
#pragma unroll
                for (int r = 0; r < 4; ++r)
                    tsum[nt][r] = fmaf(at, fmaxf(acc[r], 0.f), tsum[nt][r]);
            }
        }
        const int kh = k / 3, kw = k - 3 * kh;
#pragma unroll
        for (int nt = 0; nt < 4; ++nt) {
            const f32x4 p = *reinterpret_cast<const f32x4*>(pb0 + (kh * 66 + nt * 16 + kw) * 36);
#pragma unroll
            for (int r = 0; r < 4; ++r)
                outacc[nt][r] = fmaf(tsum[nt][r], p[r], outacc[nt][r]);
        }
        __syncthreads();
    }

    // ---- stores: 16 consecutive w per 16-lane group ----
    const int h = hbase + lt;
#pragma unroll
    for (int nt = 0; nt < 4; ++nt) {
        const int wcol = nt * 16 + c0;
#pragma unroll
        for (int r = 0; r < 4; ++r) {
            const int o = obase + o4 + r;
            out[(((size_t)b * NO + o) * NH + h) * NW + wcol] = outacc[nt][r];
        }
    }
}

extern "C" void kernel_launch(void* const* d_in, const int* in_sizes, int n_in,
                              void* d_out, int out_size, void* d_ws, size_t ws_size,
                              hipStream_t stream) {
    const float* x       = (const float*)d_in[0];
    const float* w_gen   = (const float*)d_in[1];
    const float* b_gen   = (const float*)d_in[2];
    const float* pos_enc = (const float*)d_in[3];
    float* out = (float*)d_out;

    const bool use_ws = (ws_size >= 304128);
    if (use_ws) {
        hipLaunchKernelGGL(acda_prep, dim3(36), dim3(512), 0, stream,
                           w_gen, b_gen, (unsigned char*)d_ws);
        hipLaunchKernelGGL((acda_main<true>), dim3(256), dim3(512), 0, stream,
                           x, w_gen, b_gen, pos_enc, (const unsigned char*)d_ws, out);
    } else {
        hipLaunchKernelGGL((acda_main<false>), dim3(256), dim3(512), 0, stream,
                           x, w_gen, b_gen, pos_enc, (const unsigned char*)d_ws, out);
    }
}